// Round 7
// baseline (211.786 us; speedup 1.0000x reference)
//
#include <hip/hip_runtime.h>
#include <math.h>

// Problem constants (from reference)
#define GAMMA 0.98f
#define LBDA  0.93f
#define GL    (GAMMA * LBDA)   // gamma*lambda
constexpr int B  = 2048;
constexpr int T  = 1024;

// ---------------------------------------------------------------------------
// log_pi = x[a] - logsumexp(x[0..5])
// ---------------------------------------------------------------------------
__device__ __forceinline__ float logpi(float x0, float x1, float x2,
                                       float x3, float x4, float x5, int a) {
    float m = fmaxf(fmaxf(fmaxf(x0, x1), fmaxf(x2, x3)), fmaxf(x4, x5));
    float s = __expf(x0 - m) + __expf(x1 - m) + __expf(x2 - m) +
              __expf(x3 - m) + __expf(x4 - m) + __expf(x5 - m);
    float lse = m + __logf(s);
    float r = x0;
    r = (a == 1) ? x1 : r;
    r = (a == 2) ? x2 : r;
    r = (a == 3) ? x3 : r;
    r = (a == 4) ? x4 : r;
    r = (a == 5) ? x5 : r;
    return r - lse;
}

// ---------------------------------------------------------------------------
// Fused kernel, wave-per-row: 64-thread block (1 wave) handles one batch row.
// Lane j owns timesteps t = 16j .. 16j+15 (contiguous). NO __syncthreads, NO
// LDS, no inter-wave fixup — the rounds 4-6 structure (8-wave blocks, 2
// barriers, 8-deep LDS fixup) sat at ~46us with every pipe idle; this removes
// all intra-block coupling. Logits processed in 4 chunks of 4 timesteps to
// bound live registers. Reverse recurrences (returns Rs, GAE A) via 16-step
// local affine composition (pure VALU) + one 6-round wave suffix scan.
// ---------------------------------------------------------------------------
__global__ __launch_bounds__(64, 4) void k_fused(
        const float4* __restrict__ rw4, const float4* __restrict__ vl4,
        const float*  __restrict__ vl1,
        const int4* __restrict__ dn4, const int4* __restrict__ ac4,
        const float4* __restrict__ lg4, const float4* __restrict__ lgo4,
        float* __restrict__ part_e, float* __restrict__ part_v,
        float* __restrict__ part_p) {
    int j = threadIdx.x;                 // lane 0..63
    int b = blockIdx.x;                  // row

    const float4* Lrow = lg4  + (size_t)b * 1536;   // logits row (1536 float4)
    const float4* Orow = lgo4 + (size_t)b * 1536;
    const float4* rwr  = rw4  + (size_t)b * 256;    // rewards row (256 float4)
    const float4* vlr  = vl4  + (size_t)b * 256;
    const int4*   dnr  = dn4  + (size_t)b * 256;
    const int4*   acr  = ac4  + (size_t)b * 256;

    // rewards/values for the lane's 16 steps (+1 lookahead value)
    float rw[16], v[17], r[16];
    #pragma unroll
    for (int c = 0; c < 4; ++c) {
        float4 t0 = rwr[4 * j + c];
        float4 t1 = vlr[4 * j + c];
        rw[4 * c + 0] = t0.x; rw[4 * c + 1] = t0.y;
        rw[4 * c + 2] = t0.z; rw[4 * c + 3] = t0.w;
        v[4 * c + 0] = t1.x; v[4 * c + 1] = t1.y;
        v[4 * c + 2] = t1.z; v[4 * c + 3] = t1.w;
    }
    int nidx = 16 * j + 16;
    nidx = (nidx > 1023) ? 1023 : nidx;             // j=63: loaded, unused
    v[16] = vl1[(size_t)b * 1024 + nidx];

    // chunked log-softmax gather: chunk c = timesteps 16j+4c .. +3
    float es = 0.0f;
    unsigned dbits = 0;
    #pragma unroll
    for (int c = 0; c < 4; ++c) {
        int base = 24 * j + 6 * c;
        float4 A0 = Lrow[base],     A1 = Lrow[base + 1], A2 = Lrow[base + 2];
        float4 A3 = Lrow[base + 3], A4 = Lrow[base + 4], A5 = Lrow[base + 5];
        float4 B0 = Orow[base],     B1 = Orow[base + 1], B2 = Orow[base + 2];
        float4 B3 = Orow[base + 3], B4 = Orow[base + 4], B5 = Orow[base + 5];
        int4 ac = acr[4 * j + c];
        int4 dn = dnr[4 * j + c];

        float lp0 = logpi(A0.x, A0.y, A0.z, A0.w, A1.x, A1.y, ac.x);
        float lq0 = logpi(B0.x, B0.y, B0.z, B0.w, B1.x, B1.y, ac.x);
        float lp1 = logpi(A1.z, A1.w, A2.x, A2.y, A2.z, A2.w, ac.y);
        float lq1 = logpi(B1.z, B1.w, B2.x, B2.y, B2.z, B2.w, ac.y);
        float lp2 = logpi(A3.x, A3.y, A3.z, A3.w, A4.x, A4.y, ac.z);
        float lq2 = logpi(B3.x, B3.y, B3.z, B3.w, B4.x, B4.y, ac.z);
        float lp3 = logpi(A4.z, A4.w, A5.x, A5.y, A5.z, A5.w, ac.w);
        float lq3 = logpi(B4.z, B4.w, B5.x, B5.y, B5.z, B5.w, ac.w);

        r[4 * c + 0] = __expf(lp0 - lq0);
        r[4 * c + 1] = __expf(lp1 - lq1);
        r[4 * c + 2] = __expf(lp2 - lq2);
        r[4 * c + 3] = __expf(lp3 - lq3);
        es += lp0 + lp1 + lp2 + lp3;

        dbits |= (dn.x != 0 ? 1u : 0u) << (4 * c + 0);
        dbits |= (dn.y != 0 ? 1u : 0u) << (4 * c + 1);
        dbits |= (dn.z != 0 ? 1u : 0u) << (4 * c + 2);
        dbits |= (dn.w != 0 ? 1u : 0u) << (4 * c + 3);
    }

    // ---- local suffix composition over the lane's 16 steps ----------------
    // state_{16j} = a * state_{16j+16} + b, for both recurrences
    float a1 = 1.0f, bb1 = 0.0f, a2 = 1.0f, bb2 = 0.0f;
    #pragma unroll
    for (int k = 15; k >= 0; --k) {
        bool d = (dbits >> k) & 1u;
        float c1 = d ? 0.0f : GAMMA;
        float b1 = rw[k];
        float c2 = d ? 0.0f : GL;
        float b2 = rw[k] + (d ? 0.0f : GAMMA * v[k + 1]) - v[k];
        if (j == 63 && k == 15) {   // t=T-1: Rs = d ? r : v ; A = 0
            b1 = d ? rw[15] : v[15];
            c1 = 0.0f; b2 = 0.0f; c2 = 0.0f;
        }
        bb1 = b1 + c1 * bb1;  a1 = c1 * a1;
        bb2 = b2 + c2 * bb2;  a2 = c2 * a2;
    }

    // ---- wave-level inclusive SUFFIX scan of affine maps (6 rounds) -------
    #pragma unroll
    for (int d = 1; d < 64; d <<= 1) {
        float an1 = __shfl_down(a1, d), bn1 = __shfl_down(bb1, d);
        float an2 = __shfl_down(a2, d), bn2 = __shfl_down(bb2, d);
        if (j + d < 64) {
            bb1 = a1 * bn1 + bb1;  a1 = a1 * an1;
            bb2 = a2 * bn2 + bb2;  a2 = a2 * an2;
        }
    }
    // carry entering this lane = S_{j+1}(0); lane 63 gets 0
    float b1s = __shfl_down(bb1, 1), b2s = __shfl_down(bb2, 1);
    float cin1 = (j == 63) ? 0.0f : b1s;
    float cin2 = (j == 63) ? 0.0f : b2s;

    // ---- replay with exact carries, accumulate losses ---------------------
    float vsum = 0.0f, psum = 0.0f;
    float R = cin1, A = cin2;
    #pragma unroll
    for (int k = 15; k >= 0; --k) {
        bool d = (dbits >> k) & 1u;
        float c1 = d ? 0.0f : GAMMA;
        float b1 = rw[k];
        float c2 = d ? 0.0f : GL;
        float b2 = rw[k] + (d ? 0.0f : GAMMA * v[k + 1]) - v[k];
        if (j == 63 && k == 15) {
            b1 = d ? rw[15] : v[15];
            c1 = 0.0f; b2 = 0.0f; c2 = 0.0f;
        }
        R = b1 + c1 * R;
        float dv = R - v[k];
        vsum += dv * dv;
        A = b2 + c2 * A;
        if (16 * j + k < T - 1) {
            // faithful torch clip(min=0.8,max=0.2) -> r_clipped == 0.2
            psum += fminf(r[k] * A, 0.2f * A);
        }
    }

    // ---- wave reduction, lane 0 writes the block's private slots ----------
    #pragma unroll
    for (int d = 32; d; d >>= 1) {
        es   += __shfl_xor(es, d);
        vsum += __shfl_xor(vsum, d);
        psum += __shfl_xor(psum, d);
    }
    if (j == 0) {
        part_e[b] = es;
        part_v[b] = vsum;
        part_p[b] = psum;
    }
}

// ---------------------------------------------------------------------------
// Finalize: single-block reduction of 3 x B partials -> 3 outputs.
// ---------------------------------------------------------------------------
__global__ __launch_bounds__(256) void k_fin(
        const float* __restrict__ part_e, const float* __restrict__ part_v,
        const float* __restrict__ part_p, float* __restrict__ out) {
    int tid = threadIdx.x;
    float e = 0.0f, v = 0.0f, p = 0.0f;
    for (int i = tid; i < B; i += 256) {
        e += part_e[i];
        v += part_v[i];
        p += part_p[i];
    }
    #pragma unroll
    for (int d = 32; d; d >>= 1) {
        e += __shfl_xor(e, d);
        v += __shfl_xor(v, d);
        p += __shfl_xor(p, d);
    }
    __shared__ float sm[12];
    int lane = tid & 63, wv = tid >> 6;
    if (lane == 0) { sm[wv] = e; sm[4 + wv] = v; sm[8 + wv] = p; }
    __syncthreads();
    if (tid == 0) {
        float te = sm[0] + sm[1] + sm[2] + sm[3];
        float tv = sm[4] + sm[5] + sm[6] + sm[7];
        float tp = sm[8] + sm[9] + sm[10] + sm[11];
        out[0] = -tp / (float)(B * (T - 1));   // ppo_loss
        out[1] =  tv / (float)(B * T);         // value_loss
        out[2] = -te / (float)(B * T);         // entropy_loss
    }
}

// ---------------------------------------------------------------------------
extern "C" void kernel_launch(void* const* d_in, const int* in_sizes, int n_in,
                              void* d_out, int out_size, void* d_ws, size_t ws_size,
                              hipStream_t stream) {
    const float* rewards    = (const float*)d_in[0];
    const float* values     = (const float*)d_in[1];
    const float* logits     = (const float*)d_in[2];
    const float* logits_old = (const float*)d_in[3];
    const int*   dones      = (const int*)d_in[4];
    const int*   actions    = (const int*)d_in[5];

    float* part_e = (float*)d_ws;       // B floats
    float* part_v = part_e + B;         // B floats
    float* part_p = part_v + B;         // B floats

    k_fused<<<B, 64, 0, stream>>>(
        (const float4*)rewards, (const float4*)values, values,
        (const int4*)dones, (const int4*)actions,
        (const float4*)logits, (const float4*)logits_old,
        part_e, part_v, part_p);

    k_fin<<<1, 256, 0, stream>>>(part_e, part_v, part_p, (float*)d_out);
}

// Round 8
// 155.260 us; speedup vs baseline: 1.3641x; 1.3641x over previous
//
#include <hip/hip_runtime.h>
#include <math.h>

// Problem constants (from reference)
#define GAMMA 0.98f
#define LBDA  0.93f
#define GL    (GAMMA * LBDA)   // gamma*lambda
constexpr int B  = 2048;
constexpr int T  = 1024;

// ---------------------------------------------------------------------------
// log_pi = x[a] - logsumexp(x[0..5])
// ---------------------------------------------------------------------------
__device__ __forceinline__ float logpi(float x0, float x1, float x2,
                                       float x3, float x4, float x5, int a) {
    float m = fmaxf(fmaxf(fmaxf(x0, x1), fmaxf(x2, x3)), fmaxf(x4, x5));
    float s = __expf(x0 - m) + __expf(x1 - m) + __expf(x2 - m) +
              __expf(x3 - m) + __expf(x4 - m) + __expf(x5 - m);
    float lse = m + __logf(s);
    float r = x0;
    r = (a == 1) ? x1 : r;
    r = (a == 2) ? x2 : r;
    r = (a == 3) ? x3 : r;
    r = (a == 4) ? x4 : r;
    r = (a == 5) ? x5 : r;
    return r - lse;
}

// LDS float4-index swizzle (round-2 validated: SQ_LDS_BANK_CONFLICT == 0):
// permutes within aligned groups of 8 -> stride-1 writes stay conflict-free,
// stride-3 reads (lanes 8 apart alias banks) get spread across 8 bank groups.
__device__ __forceinline__ int sw(int m) { return m ^ ((m >> 3) & 7); }

// ---------------------------------------------------------------------------
// Fused kernel: one block (512 threads = 8 waves) per batch row; thread j
// owns timesteps t = 2j, 2j+1. Logits are staged through WAVE-PRIVATE LDS:
// each wave loads its 128 timesteps' logits (192 float4/array) with
// perfectly-coalesced stride-1 lane loads, writes its own 6 KB region, and
// reads back at stride 3 (swizzled). Same-wave ds ordering via lgkmcnt only
// -- NO __syncthreads in the staging path (round 4's cross-wave barriers and
// round 5-6's 48-B-stride divergent loads both sat at ~46us).
// Reverse recurrences (returns Rs, GAE A) via affine-map suffix composition:
// local map -> wave suffix scan -> 8-wave LDS fixup (the single barrier) ->
// replay with exact carry. Block partials -> private slots (no atomics).
// ---------------------------------------------------------------------------
__global__ __launch_bounds__(512) void k_fused(
        const float2* __restrict__ rw2, const float2* __restrict__ vl2,
        const float*  __restrict__ vl1,
        const int2* __restrict__ dn2, const int2* __restrict__ ac2,
        const float4* __restrict__ lg4, const float4* __restrict__ lgo4,
        float* __restrict__ part_e, float* __restrict__ part_v,
        float* __restrict__ part_p) {
    int j = threadIdx.x;
    int b = blockIdx.x;
    int L = j & 63, w = j >> 6;          // lane, wave

    const float4* Lrow = lg4  + (size_t)b * 1536;   // 1536 float4 per row
    const float4* Orow = lgo4 + (size_t)b * 1536;
    int rbase = b * 512 + j;                        // float2/int2 row index
    int wbase = w * 192;                            // wave's float4 offset

    // coalesced global loads (lane-stride 16 B), all issued up front
    float4 g0 = Lrow[wbase + L], g1 = Lrow[wbase + 64 + L], g2 = Lrow[wbase + 128 + L];
    float4 h0 = Orow[wbase + L], h1 = Orow[wbase + 64 + L], h2 = Orow[wbase + 128 + L];
    float2 rw = rw2[rbase], vlv = vl2[rbase];
    int2 dn = dn2[rbase], aa = ac2[rbase];
    int vidx = 2 * j + 2;                           // values[t+2]
    vidx = (vidx > 1022) ? 1022 : vidx;             // j=511: loaded but unused
    float vnext = vl1[(size_t)b * T + vidx];

    // wave-private staging: [w][0..192) = logits, [w][192..384) = logits_old
    __shared__ float4 sb[8][384];                   // 48 KB
    __shared__ float wa1[8], wb1[8], wa2[8], wb2[8];
    __shared__ float red[24];

    sb[w][sw(L)]            = g0;
    sb[w][sw(64 + L)]       = g1;
    sb[w][sw(128 + L)]      = g2;
    sb[w][192 + sw(L)]      = h0;
    sb[w][192 + sw(64 + L)] = h1;
    sb[w][192 + sw(128 + L)] = h2;
    // same-wave ds_write -> ds_read: ordered by compiler lgkmcnt, no barrier

    int m = 3 * L;                                  // wave-local float4 index
    float4 A0 = sb[w][sw(m)], A1 = sb[w][sw(m + 1)], A2 = sb[w][sw(m + 2)];
    float4 B0 = sb[w][192 + sw(m)], B1 = sb[w][192 + sw(m + 1)], B2 = sb[w][192 + sw(m + 2)];

    float lp0  = logpi(A0.x, A0.y, A0.z, A0.w, A1.x, A1.y, aa.x);
    float lp1  = logpi(A1.z, A1.w, A2.x, A2.y, A2.z, A2.w, aa.y);
    float lpo0 = logpi(B0.x, B0.y, B0.z, B0.w, B1.x, B1.y, aa.x);
    float lpo1 = logpi(B1.z, B1.w, B2.x, B2.y, B2.z, B2.w, aa.y);
    float rr0 = __expf(lp0 - lpo0), rr1 = __expf(lp1 - lpo1);

    // ---- per-thread affine maps for the two recurrences -------------------
    float rwk[2] = {rw.x, rw.y};
    float vk[3]  = {vlv.x, vlv.y, vnext};
    int   dk[2]  = {dn.x, dn.y};

    float b1[2], c1[2], b2[2], c2[2];
    #pragma unroll
    for (int k = 0; k < 2; ++k) {
        bool d = dk[k] != 0;
        c1[k] = d ? 0.0f : GAMMA;
        b1[k] = rwk[k];
        c2[k] = d ? 0.0f : GL;
        b2[k] = rwk[k] + (d ? 0.0f : GAMMA * vk[k + 1]) - vk[k];  // td error
    }
    if (j == 511) {  // t = T-1: Rs[T-1] = d ? r : v ; A[T-1] = 0
        b1[1] = dk[1] ? rwk[1] : vk[1];
        c1[1] = 0.0f;
        b2[1] = 0.0f;
        c2[1] = 0.0f;
    }

    // local suffix composition over k = 1..0
    float a1 = 1.0f, bb1 = 0.0f, a2 = 1.0f, bb2 = 0.0f;
    #pragma unroll
    for (int k = 1; k >= 0; --k) {
        bb1 = b1[k] + c1[k] * bb1;  a1 = c1[k] * a1;
        bb2 = b2[k] + c2[k] * bb2;  a2 = c2[k] * a2;
    }

    // wave-level inclusive SUFFIX scan of affine maps
    #pragma unroll
    for (int d = 1; d < 64; d <<= 1) {
        float an1 = __shfl_down(a1, d), bn1 = __shfl_down(bb1, d);
        float an2 = __shfl_down(a2, d), bn2 = __shfl_down(bb2, d);
        if (L + d < 64) {
            bb1 = a1 * bn1 + bb1;  a1 = a1 * an1;
            bb2 = a2 * bn2 + bb2;  a2 = a2 * an2;
        }
    }
    if (L == 0) { wa1[w] = a1; wb1[w] = bb1; wa2[w] = a2; wb2[w] = bb2; }
    float a1s = __shfl_down(a1, 1), b1s = __shfl_down(bb1, 1);
    float a2s = __shfl_down(a2, 1), b2s = __shfl_down(bb2, 1);
    __syncthreads();                                // the one barrier

    // carry entering this wave's high end (apply later waves' maps to 0)
    float x1 = 0.0f, x2 = 0.0f;
    for (int w2 = 7; w2 > w; --w2) {
        x1 = wa1[w2] * x1 + wb1[w2];
        x2 = wa2[w2] * x2 + wb2[w2];
    }
    float cin1 = (L == 63) ? x1 : (a1s * x1 + b1s);
    float cin2 = (L == 63) ? x2 : (a2s * x2 + b2s);

    // replay with exact carries, accumulate losses
    float rrk[2] = {rr0, rr1};
    float vsum = 0.0f, psum = 0.0f;
    float R = cin1, A = cin2;
    #pragma unroll
    for (int k = 1; k >= 0; --k) {
        R = b1[k] + c1[k] * R;
        float dv = R - vk[k];
        vsum += dv * dv;
        A = b2[k] + c2[k] * A;
        if (2 * j + k < T - 1) {
            // faithful torch clip(min=0.8,max=0.2) -> r_clipped == 0.2
            psum += fminf(rrk[k] * A, 0.2f * A);
        }
    }
    float es = lp0 + lp1;

    #pragma unroll
    for (int d = 32; d; d >>= 1) {
        es   += __shfl_xor(es, d);
        vsum += __shfl_xor(vsum, d);
        psum += __shfl_xor(psum, d);
    }
    if (L == 0) { red[w] = es; red[8 + w] = vsum; red[16 + w] = psum; }
    __syncthreads();
    if (j == 0) {
        float te = 0.0f, tv = 0.0f, tp = 0.0f;
        #pragma unroll
        for (int w2 = 0; w2 < 8; ++w2) {
            te += red[w2]; tv += red[8 + w2]; tp += red[16 + w2];
        }
        part_e[b] = te;
        part_v[b] = tv;
        part_p[b] = tp;
    }
}

// ---------------------------------------------------------------------------
// Finalize: single-block reduction of 3 x B partials -> 3 outputs.
// ---------------------------------------------------------------------------
__global__ __launch_bounds__(256) void k_fin(
        const float* __restrict__ part_e, const float* __restrict__ part_v,
        const float* __restrict__ part_p, float* __restrict__ out) {
    int tid = threadIdx.x;
    float e = 0.0f, v = 0.0f, p = 0.0f;
    for (int i = tid; i < B; i += 256) {
        e += part_e[i];
        v += part_v[i];
        p += part_p[i];
    }
    #pragma unroll
    for (int d = 32; d; d >>= 1) {
        e += __shfl_xor(e, d);
        v += __shfl_xor(v, d);
        p += __shfl_xor(p, d);
    }
    __shared__ float sm[12];
    int lane = tid & 63, wv = tid >> 6;
    if (lane == 0) { sm[wv] = e; sm[4 + wv] = v; sm[8 + wv] = p; }
    __syncthreads();
    if (tid == 0) {
        float te = sm[0] + sm[1] + sm[2] + sm[3];
        float tv = sm[4] + sm[5] + sm[6] + sm[7];
        float tp = sm[8] + sm[9] + sm[10] + sm[11];
        out[0] = -tp / (float)(B * (T - 1));   // ppo_loss
        out[1] =  tv / (float)(B * T);         // value_loss
        out[2] = -te / (float)(B * T);         // entropy_loss
    }
}

// ---------------------------------------------------------------------------
extern "C" void kernel_launch(void* const* d_in, const int* in_sizes, int n_in,
                              void* d_out, int out_size, void* d_ws, size_t ws_size,
                              hipStream_t stream) {
    const float* rewards    = (const float*)d_in[0];
    const float* values     = (const float*)d_in[1];
    const float* logits     = (const float*)d_in[2];
    const float* logits_old = (const float*)d_in[3];
    const int*   dones      = (const int*)d_in[4];
    const int*   actions    = (const int*)d_in[5];

    float* part_e = (float*)d_ws;       // B floats
    float* part_v = part_e + B;         // B floats
    float* part_p = part_v + B;         // B floats

    k_fused<<<B, 512, 0, stream>>>(
        (const float2*)rewards, (const float2*)values, values,
        (const int2*)dones, (const int2*)actions,
        (const float4*)logits, (const float4*)logits_old,
        part_e, part_v, part_p);

    k_fin<<<1, 256, 0, stream>>>(part_e, part_v, part_p, (float*)d_out);
}